// Round 11
// baseline (68.946 us; speedup 1.0000x reference)
//
#include <hip/hip_runtime.h>
#include <hip/hip_bf16.h>
#include <hip/hip_fp16.h>
#include <math.h>

// ---- types ----
using f32x4  = __attribute__((ext_vector_type(4))) float;
using half8  = __attribute__((ext_vector_type(8))) _Float16;
using uint4v = __attribute__((ext_vector_type(4))) unsigned int;

#define WAITV(N) asm volatile("s_waitcnt vmcnt(" #N ")" ::: "memory")
#define LGKM0    asm volatile("s_waitcnt lgkmcnt(0)" ::: "memory")
#define SBAR     __builtin_amdgcn_s_barrier()

__device__ __forceinline__ unsigned short f32_to_f16u(float f) {
  return __half_as_ushort(__float2half(f));
}
__device__ __forceinline__ float f16u_to_f32(unsigned short h) {
  return __half2float(__ushort_as_half(h));
}
__device__ __forceinline__ unsigned int pk2(float a, float b) {
  return (unsigned int)f32_to_f16u(a) | ((unsigned int)f32_to_f16u(b) << 16);
}
__device__ __forceinline__ f32x4 mfma16(half8 a, half8 b, f32x4 c) {
  return __builtin_amdgcn_mfma_f32_16x16x32_f16(a, b, c, 0, 0, 0);
}
__device__ __forceinline__ void gload_lds16(void* lds, const void* g) {
  __builtin_amdgcn_global_load_lds(
      (const __attribute__((address_space(1))) unsigned int*)g,
      (__attribute__((address_space(3))) unsigned int*)lds, 16, 0, 0);
}
__device__ __forceinline__ float gelu_exact(float x) {
  return 0.5f * x * (1.0f + erff(x * 0.70710678118654752440f));
}

// ---- problem constants ----
// B=32768, D=768, H1=256, E=128, N=500(pad 512), K_imp=902(pad 960)

// ---------------------------------------------------------------------------
// prep (unchanged from r10)
// ---------------------------------------------------------------------------
__global__ __launch_bounds__(256) void k_prep(
    const float* __restrict__ enc_w1, const float* __restrict__ enc_w2,
    const float* __restrict__ imp_w1, const float* __restrict__ cent,
    const float* __restrict__ reward, const float* __restrict__ tsp,
    const float* __restrict__ emo,
    unsigned short* __restrict__ W1T, unsigned short* __restrict__ W2T,
    unsigned short* __restrict__ impW1T, unsigned short* __restrict__ centC,
    float* __restrict__ c_n, unsigned short* __restrict__ tail) {
  __shared__ float ld[64][65];
  const int bx = blockIdx.x, t = threadIdx.x;
  if (bx < 48) {
    int tk = bx % 12, tn = bx / 12;
    int k0 = tk * 64, n0 = tn * 64;
    int cn = t & 63, r4 = t >> 6;
#pragma unroll
    for (int pass = 0; pass < 16; ++pass) {
      int kk = pass * 4 + r4;
      ld[kk][cn] = enc_w1[(size_t)(k0 + kk) * 256 + n0 + cn];
    }
    __syncthreads();
    int ck = t & 63, rn4 = t >> 6;
#pragma unroll
    for (int pass = 0; pass < 16; ++pass) {
      int nn = pass * 4 + rn4;
      W1T[(size_t)(n0 + nn) * 768 + k0 + ck] = f32_to_f16u(ld[ck][nn]);
    }
    return;
  }
  int idx = (bx - 48) * 256 + t;
  if (idx < 128 * 256) {
    int n = idx >> 8, k = idx & 255;
    W2T[idx] = f32_to_f16u(enc_w2[k * 128 + n]);
  }
  if (idx < 64 * 960) {
    int n = idx / 960, k = idx - n * 960;
    impW1T[idx] = (k < 902) ? f32_to_f16u(imp_w1[k * 64 + n]) : (unsigned short)0;
  }
  if (idx < 512 * 128) {
    int n = idx >> 7, k = idx & 127;
    centC[idx] = (n < 500) ? f32_to_f16u(cent[n * 128 + k]) : (unsigned short)0;
  }
  if (idx < 512) {
    float s = 0.f;
    if (idx < 500) {
      const f32x4* p = (const f32x4*)(cent + idx * 128);
#pragma unroll 8
      for (int j = 0; j < 32; ++j) {
        f32x4 v = p[j];
#pragma unroll
        for (int e = 0; e < 4; ++e) {
          float q = (float)(_Float16)v[e];
          s += q * q;
        }
      }
    }
    c_n[idx] = sqrtf(s);
  }
  if (idx < 32768) {
    f32x4 e4 = *(const f32x4*)(emo + (size_t)idx * 4);
    unsigned short* tp = tail + (size_t)idx * 8;
    tp[0] = f32_to_f16u(reward[idx]);
    tp[1] = f32_to_f16u(tsp[idx]);
    tp[2] = f32_to_f16u(e4[0]); tp[3] = f32_to_f16u(e4[1]);
    tp[4] = f32_to_f16u(e4[2]); tp[5] = f32_to_f16u(e4[3]);
    tp[6] = 0; tp[7] = 0;
  }
}

// ---------------------------------------------------------------------------
// k_fused: main loop = EXACT r6/r10 structure. Epilogue with overlapped
// staging: W2T kh0 prefetched during tail steps (B2(14) moved to buf1 so
// [32K,65.5K) is dead); kh1 flight covered by imp-final; cent = 8x16KB
// ring, dbuf, 1-chunk-ahead prefetch covered by top-5 VALU.
// LDS map (epilogue): h1 [0,32K) -> enc [0,16K); W2T [32K,64K); cent ring
// [16K,32K)+[32K,48K); s_pn@65536 s_en@67584 s_p@67840 s_mk@68864.
// ---------------------------------------------------------------------------
__global__ __launch_bounds__(512, 4) void k_fused(
    const float* __restrict__ cue, const float* __restrict__ internal,
    const float* __restrict__ emo,
    const unsigned short* __restrict__ W1T, const unsigned short* __restrict__ impW1T,
    const unsigned short* __restrict__ tail,
    const unsigned short* __restrict__ W2T, const unsigned short* __restrict__ centC,
    const float* __restrict__ c_n,
    const float* __restrict__ b1, const float* __restrict__ b2,
    const float* __restrict__ ib1, const float* __restrict__ iw2,
    const float* __restrict__ ib2, float* __restrict__ out) {
  __shared__ unsigned char sm[73728];
  const int t = threadIdx.x;
  const int lane = t & 63, w = t >> 6;
  const int wr = w >> 2, wc = w & 3;
  const int g = lane >> 4, c = lane & 15;
  const int row0 = blockIdx.x * 64;

  const int srow = t >> 3, q8 = t & 7;
  const int abyte = srow * 128 + q8 * 16;
  const int aswz = (srow & 7) << 4;
  const int myrow = row0 + srow;

  f32x4 aLo, aHi;
  auto issueA = [&](int j) {
    const float* s = (j < 12)
        ? (cue + (size_t)myrow * 768 + j * 64 + q8 * 8)
        : (internal + (size_t)myrow * 128 + (j - 12) * 64 + q8 * 8);
    aLo = *(const f32x4*)s;
    aHi = *(const f32x4*)(s + 4);
  };
  auto convWrite = [&](int buf) {
    uint4v u = {pk2(aLo[0], aLo[1]), pk2(aLo[2], aLo[3]),
                pk2(aHi[0], aHi[1]), pk2(aHi[2], aHi[3])};
    *(uint4v*)(sm + buf * 8192 + (abyte ^ aswz)) = u;
  };
  auto issueB1 = [&](int j) {
#pragma unroll
    for (int i = 0; i < 4; ++i) {
      int L = i * 8192 + t * 16;
      int nl = L >> 7, x = L & 127;
      gload_lds16(sm + 24576 + i * 8192 + w * 1024,
                  (const unsigned char*)W1T + ((size_t)nl * 768 + j * 64) * 2 +
                      (x ^ ((nl & 7) << 4)));
    }
  };
  auto issueB2 = [&](int j, int buf) {
    int L = t * 16, nl = L >> 7, x = L & 127;
    gload_lds16(sm + 57344 + buf * 8192 + w * 1024,
                (const unsigned char*)impW1T + (size_t)nl * 1920 + j * 128 +
                    (x ^ ((nl & 7) << 4)));
  };
  auto issueW2T = [&](int kh) {
#pragma unroll
    for (int i = 0; i < 4; ++i) {
      int L = i * 8192 + t * 16;
      int nl = L >> 8, x = L & 255;
      gload_lds16(sm + 32768 + i * 8192 + w * 1024,
                  (const unsigned char*)W2T + (size_t)nl * 512 + kh * 256 +
                      (x ^ ((nl & 7) << 4)));
    }
  };
  auto issueC = [&](int ch, int buf) {   // 64-row cent chunk -> 16KB ring
#pragma unroll
    for (int i = 0; i < 2; ++i) {
      int L = i * 8192 + t * 16;
      int nl = L >> 8, x = L & 255;
      gload_lds16(sm + 16384 + buf * 16384 + i * 8192 + w * 1024,
                  (const unsigned char*)centC + (size_t)(ch * 64 + nl) * 256 +
                      (x ^ ((nl & 7) << 4)));
    }
  };

  f32x4 acc1[2][4];
  f32x4 acc2[2];
#pragma unroll
  for (int i = 0; i < 2; ++i) {
    acc2[i] = f32x4{0.f, 0.f, 0.f, 0.f};
#pragma unroll
    for (int j = 0; j < 4; ++j) acc1[i][j] = f32x4{0.f, 0.f, 0.f, 0.f};
  }

  auto mfma_step = [&](int abuf, int b2buf, bool enc) {
    const unsigned char* Ab  = sm + abuf * 8192;
    const unsigned char* Bb2 = sm + 57344 + b2buf * 8192;
#pragma unroll
    for (int ks = 0; ks < 2; ++ks) {
      half8 af[2];
#pragma unroll
      for (int mf = 0; mf < 2; ++mf) {
        int m = wr * 32 + mf * 16 + c;
        af[mf] = *(const half8*)(Ab + m * 128 + ((ks * 64 + g * 16) ^ ((m & 7) << 4)));
      }
      {
        int n2 = wc * 16 + c;
        half8 b2f = *(const half8*)(Bb2 + n2 * 128 + ((ks * 64 + g * 16) ^ ((n2 & 7) << 4)));
        acc2[0] = mfma16(af[0], b2f, acc2[0]);
        acc2[1] = mfma16(af[1], b2f, acc2[1]);
      }
      if (enc) {
#pragma unroll
        for (int nf = 0; nf < 4; ++nf) {
          int n = wc * 64 + nf * 16 + c;
          half8 bf = *(const half8*)(sm + 24576 + n * 128 +
                                     ((ks * 64 + g * 16) ^ ((n & 7) << 4)));
          acc1[0][nf] = mfma16(af[0], bf, acc1[0][nf]);
          acc1[1][nf] = mfma16(af[1], bf, acc1[1][nf]);
        }
      }
    }
  };

  // ---- prologue ----
  {
    uint4v tl = {0u, 0u, 0u, 0u};
    if (q8 == 0) tl = *(const uint4v*)(tail + (size_t)myrow * 8);
    issueA(0); issueB1(0); issueB2(0, 0);
    *(uint4v*)(sm + 16384 + (abyte ^ aswz)) = tl;
    convWrite(0);
    issueA(1); issueB2(1, 1);
    WAITV(3);
    LGKM0;
    SBAR;
  }

  int p = 0;
  for (int it = 0; it < 12; ++it) {
    mfma_step(p, p, true);
    convWrite(p ^ 1);
    LGKM0;
    SBAR;
    if (it < 11) issueB1(it + 1);
    issueA(it + 2);
    issueB2(it + 2, p);
    WAITV(3);
    SBAR;
    p ^= 1;
  }
  // ---- tail steps 12..14 with W2T kh0 prefetch ----
  mfma_step(0, 0, false);              // tile 12 (A buf0, B2 buf0)
  convWrite(1);                        // A(13) -> abuf1 (drains A regs)
  LGKM0;
  WAITV(0);                            // B2(13) landed (flew a full step)
  SBAR;
  mfma_step(1, 1, false);              // tile 13 (A buf1, B2 buf1)
  LGKM0;
  SBAR;                                // buf1 reads done
  issueB2(14, 1);                      // -> buf1
  issueW2T(0);                         // [32K,64K): B1 + B2 buf0 dead
  WAITV(4);                            // B2(14) landed; W2T(4) in flight
  SBAR;
  mfma_step(2, 1, false);              // tile 14 (A tail slot, B2 buf1)
  LGKM0;
  SBAR;                                // tail/A reads done; [0,32K) free

  // ================= EPILOGUE =================
  float* s_pn = (float*)(sm + 65536);               // [64][8]
  float* s_en = (float*)(sm + 67584);               // [64]
  float* s_p  = (float*)(sm + 67840);               // [64][4]
  unsigned int* s_mk = (unsigned int*)(sm + 68864); // [64][2][5]

  // h1 tile [64][512B] swz -> [0,32K) + imp partials (heavy VALU; W2T flying)
  {
    float b1v = ib1[wc * 16 + c];
    float w2v = iw2[wc * 16 + c];
#pragma unroll
    for (int mf = 0; mf < 2; ++mf)
#pragma unroll
      for (int rr = 0; rr < 4; ++rr) {
        float v = gelu_exact(acc2[mf][rr] + b1v) * w2v;
        v += __shfl_xor(v, 1);
        v += __shfl_xor(v, 2);
        v += __shfl_xor(v, 4);
        v += __shfl_xor(v, 8);
        if (c == 0) s_p[(wr * 32 + mf * 16 + g * 4 + rr) * 4 + wc] = v;
      }
    float bias1[4];
#pragma unroll
    for (int nf = 0; nf < 4; ++nf) bias1[nf] = b1[wc * 64 + nf * 16 + c];
#pragma unroll
    for (int mf = 0; mf < 2; ++mf)
#pragma unroll
      for (int nf = 0; nf < 4; ++nf)
#pragma unroll
        for (int rr = 0; rr < 4; ++rr) {
          int row = wr * 32 + mf * 16 + g * 4 + rr;
          int col = wc * 64 + nf * 16 + c;
          float x = gelu_exact(acc1[mf][nf][rr] + bias1[nf]);
          *(unsigned short*)(sm + row * 512 + ((col * 2) ^ ((row & 7) << 4))) =
              f32_to_f16u(x);
        }
  }
  WAITV(0);            // W2T kh0 landed (flight covered by section above)
  LGKM0;
  SBAR;                // h1 + s_p + W2T visible

  // enc2 kh0 (K 0..127)
  f32x4 acc_e[4];
#pragma unroll
  for (int mf = 0; mf < 4; ++mf) acc_e[mf] = f32x4{0.f, 0.f, 0.f, 0.f};
#pragma unroll
  for (int ks = 0; ks < 4; ++ks) {
    half8 af[4];
#pragma unroll
    for (int mf = 0; mf < 4; ++mf) {
      int m = mf * 16 + c;
      af[mf] = *(const half8*)(sm + m * 512 + ((ks * 64 + g * 16) ^ ((m & 7) << 4)));
    }
    int nl = w * 16 + c;
    half8 bf = *(const half8*)(sm + 32768 + nl * 256 +
                               ((ks * 64 + g * 16) ^ ((nl & 7) << 4)));
#pragma unroll
    for (int mf = 0; mf < 4; ++mf) acc_e[mf] = mfma16(af[mf], bf, acc_e[mf]);
  }
  LGKM0;
  SBAR;                // W2T kh0 reads done
  issueW2T(1);         // restage [32K,64K)
  // imp final (t<64) covers kh1 flight
  if (t < 64) {
    float ssum = s_p[t * 4 + 0] + s_p[t * 4 + 1] + s_p[t * 4 + 2] + s_p[t * 4 + 3];
    int rowA = row0 + t;
    float z = ssum + ib2[0];
    float sig = 1.0f / (1.0f + expf(-z));
    f32x4 e4 = *(const f32x4*)(emo + (size_t)rowA * 4);
    float m4 = 0.25f * (e4[0] + e4[1] + e4[2] + e4[3]);
    out[(size_t)rowA * 6 + 5] = sig * m4;
  }
  WAITV(1);            // kh1 landed (leave out-store in flight)
  SBAR;
  // enc2 kh1 (K 128..255)
#pragma unroll
  for (int ks = 0; ks < 4; ++ks) {
    half8 af[4];
#pragma unroll
    for (int mf = 0; mf < 4; ++mf) {
      int m = mf * 16 + c;
      af[mf] = *(const half8*)(sm + m * 512 +
                               ((256 + ks * 64 + g * 16) ^ ((m & 7) << 4)));
    }
    int nl = w * 16 + c;
    half8 bf = *(const half8*)(sm + 32768 + nl * 256 +
                               ((ks * 64 + g * 16) ^ ((nl & 7) << 4)));
#pragma unroll
    for (int mf = 0; mf < 4; ++mf) acc_e[mf] = mfma16(af[mf], bf, acc_e[mf]);
  }
  LGKM0;
  SBAR;                // h1 reads done; [0,16K) free for enc tile

  // enc tile [64][256B] swz -> [0,16K) + norms from registers
  {
    float bias2 = b2[w * 16 + c];
#pragma unroll
    for (int mf = 0; mf < 4; ++mf)
#pragma unroll
      for (int rr = 0; rr < 4; ++rr) {
        int row = mf * 16 + g * 4 + rr;
        float x = acc_e[mf][rr] + bias2;
        unsigned short hv = f32_to_f16u(x);
        float xr = f16u_to_f32(hv);
        *(unsigned short*)(sm + row * 256 + (((w * 16 + c) * 2) ^ ((row & 7) << 4))) = hv;
        float v = xr * xr;
        v += __shfl_xor(v, 1);
        v += __shfl_xor(v, 2);
        v += __shfl_xor(v, 4);
        v += __shfl_xor(v, 8);
        if (c == 0) s_pn[row * 8 + w] = v;
      }
  }
  LGKM0;
  SBAR;
  issueC(0, 0);        // cent chunk 0 -> ring0 [16K,32K)
  if (t < 64) {        // s_en (covers chunk0 flight)
    float s = 0.f;
#pragma unroll
    for (int i = 0; i < 8; ++i) s += s_pn[t * 8 + i];
    s_en[t] = sqrtf(s);
  }
  WAITV(0);
  LGKM0;
  SBAR;                // chunk0 + s_en + enc tile visible

  // sims: wave pair (w, w+4) shares rows (w&3)*16..+16; halfsel = 32-col split
  const int rlb = (w & 3) * 16;
  const int halfsel = w >> 2;
  float en[4];
#pragma unroll
  for (int r = 0; r < 4; ++r) en[r] = s_en[rlb + g * 4 + r];
  half8 af2[4];
  {
    int rl = rlb + c;
#pragma unroll
    for (int kk = 0; kk < 4; ++kk)
      af2[kk] = *(const half8*)(sm + rl * 256 +
                                ((kk * 64 + g * 16) ^ ((rl & 7) << 4)));
  }

  unsigned int top5[4][5];
#pragma unroll
  for (int r = 0; r < 4; ++r)
#pragma unroll
    for (int s5 = 0; s5 < 5; ++s5) top5[r][s5] = 0u;

#pragma unroll
  for (int ch = 0; ch < 8; ++ch) {
    if (ch < 7) issueC(ch + 1, (ch + 1) & 1);
    const unsigned char* Cb = sm + 16384 + (ch & 1) * 16384;
#pragma unroll
    for (int nfc = 0; nfc < 2; ++nfc) {
      int nl = halfsel * 32 + nfc * 16 + c;
      const unsigned char* bbase = Cb + nl * 256;
      int swz = (nl & 7) << 4;
      f32x4 acc = f32x4{0.f, 0.f, 0.f, 0.f};
#pragma unroll
      for (int kk = 0; kk < 4; ++kk) {
        half8 bf = *(const half8*)(bbase + ((kk * 64 + g * 16) ^ swz));
        acc = mfma16(af2[kk], bf, acc);
      }
      int col = ch * 64 + nl;
      float cnv = c_n[col];
#pragma unroll
      for (int r = 0; r < 4; ++r) {
        float denom = fmaxf(en[r] * cnv, 1e-8f);
        float v = acc[r] * __builtin_amdgcn_rcpf(denom);
        unsigned int u = __float_as_uint(v);
        u = (u & 0x80000000u) ? ~u : (u | 0x80000000u);
        unsigned int k = (col < 500) ? ((u & 0xFFFFFE00u) | (unsigned)col) : 0u;
        unsigned int t0 = top5[r][0], t1 = top5[r][1], t2 = top5[r][2],
                     t3 = top5[r][3], t4 = top5[r][4];
        top5[r][0] = (k > t0) ? k : t0;
        top5[r][1] = (k > t0) ? t0 : ((k > t1) ? k : t1);
        top5[r][2] = (k > t1) ? t1 : ((k > t2) ? k : t2);
        top5[r][3] = (k > t2) ? t2 : ((k > t3) ? k : t3);
        top5[r][4] = (k > t3) ? t3 : ((k > t4) ? k : t4);
      }
    }
    if (ch < 7) {
      WAITV(0);        // chunk ch+1 landed (flight covered by MFMA+insert)
      SBAR;            // visible to all; ring swap safe
    }
  }

  // per-wave extraction -> s_mk[row][halfsel][5]
#pragma unroll
  for (int r = 0; r < 4; ++r) {
    int row = rlb + g * 4 + r;
    unsigned int h0 = top5[r][0], h1v = top5[r][1], h2 = top5[r][2],
                 h3 = top5[r][3], h4 = top5[r][4];
#pragma unroll
    for (int it5 = 0; it5 < 5; ++it5) {
      unsigned int best = h0;
#pragma unroll
      for (int s = 1; s < 16; s <<= 1) {
        unsigned int o = __shfl_xor(best, s);
        best = (o > best) ? o : best;
      }
      if (c == 0) s_mk[(row * 2 + halfsel) * 5 + it5] = best;
      bool pop = (h0 == best);
      h0 = pop ? h1v : h0;
      h1v = pop ? h2 : h1v;
      h2 = pop ? h3 : h2;
      h3 = pop ? h4 : h3;
      h4 = pop ? 0u : h4;
    }
  }
  LGKM0;
  SBAR;

  // merge two sorted 5-lists per row -> out cols 0..4
  if (t < 64) {
    const unsigned int* A = s_mk + (t * 2 + 0) * 5;
    const unsigned int* B = s_mk + (t * 2 + 1) * 5;
    int ia = 0, ib = 0;
#pragma unroll
    for (int o = 0; o < 5; ++o) {
      unsigned int a = (ia < 5) ? A[ia] : 0u;
      unsigned int b = (ib < 5) ? B[ib] : 0u;
      unsigned int best;
      if (a >= b) { best = a; ++ia; } else { best = b; ++ib; }
      unsigned int m = best & 0xFFFFFE00u;
      unsigned int uu = (m & 0x80000000u) ? (m ^ 0x80000000u) : ~m;
      out[(size_t)(row0 + t) * 6 + o] = __uint_as_float(uu);
    }
  }
}

// ---------------------------------------------------------------------------
extern "C" void kernel_launch(void* const* d_in, const int* in_sizes, int n_in,
                              void* d_out, int out_size, void* d_ws, size_t ws_size,
                              hipStream_t stream) {
  (void)in_sizes; (void)n_in; (void)out_size; (void)ws_size;
  const float* cue      = (const float*)d_in[0];
  const float* internal = (const float*)d_in[1];
  const float* reward   = (const float*)d_in[2];
  const float* tsp      = (const float*)d_in[3];
  const float* emo      = (const float*)d_in[4];
  const float* cent     = (const float*)d_in[5];
  const float* enc_w1   = (const float*)d_in[6];
  const float* enc_b1   = (const float*)d_in[7];
  const float* enc_w2   = (const float*)d_in[8];
  const float* enc_b2   = (const float*)d_in[9];
  const float* imp_w1   = (const float*)d_in[10];
  const float* imp_b1   = (const float*)d_in[11];
  const float* imp_w2   = (const float*)d_in[12];
  const float* imp_b2   = (const float*)d_in[13];
  float* out = (float*)d_out;

  unsigned char* ws = (unsigned char*)d_ws;
  unsigned short* W1T    = (unsigned short*)(ws + 0);        // 393216
  unsigned short* W2T    = (unsigned short*)(ws + 393216);   //  65536
  unsigned short* impW1T = (unsigned short*)(ws + 458752);   // 122880
  unsigned short* centC  = (unsigned short*)(ws + 581632);   // 131072
  float*          c_n    = (float*)(ws + 712704);            //   2048
  unsigned short* tail   = (unsigned short*)(ws + 714752);   // 524288

  k_prep<<<304, 256, 0, stream>>>(enc_w1, enc_w2, imp_w1, cent, reward, tsp, emo,
                                  W1T, W2T, impW1T, centC, c_n, tail);
  k_fused<<<512, 512, 0, stream>>>(cue, internal, emo, W1T, impW1T, tail,
                                   W2T, centC, c_n, enc_b1, enc_b2,
                                   imp_b1, imp_w2, imp_b2, out);
}

// Round 12
// 63.483 us; speedup vs baseline: 1.0861x; 1.0861x over previous
//
#include <hip/hip_runtime.h>
#include <hip/hip_bf16.h>
#include <hip/hip_fp16.h>
#include <math.h>

// ---- types ----
using f32x4  = __attribute__((ext_vector_type(4))) float;
using half8  = __attribute__((ext_vector_type(8))) _Float16;
using uint4v = __attribute__((ext_vector_type(4))) unsigned int;

#define WAITV(N) asm volatile("s_waitcnt vmcnt(" #N ")" ::: "memory")
#define LGKM0    asm volatile("s_waitcnt lgkmcnt(0)" ::: "memory")

__device__ __forceinline__ unsigned short f32_to_f16u(float f) {
  return __half_as_ushort(__float2half(f));
}
__device__ __forceinline__ float f16u_to_f32(unsigned short h) {
  return __half2float(__ushort_as_half(h));
}
__device__ __forceinline__ unsigned int pk2(float a, float b) {
  return (unsigned int)f32_to_f16u(a) | ((unsigned int)f32_to_f16u(b) << 16);
}
__device__ __forceinline__ f32x4 mfma16(half8 a, half8 b, f32x4 c) {
  return __builtin_amdgcn_mfma_f32_16x16x32_f16(a, b, c, 0, 0, 0);
}
__device__ __forceinline__ void gload_lds16(void* lds, const void* g) {
  __builtin_amdgcn_global_load_lds(
      (const __attribute__((address_space(1))) unsigned int*)g,
      (__attribute__((address_space(3))) unsigned int*)lds, 16, 0, 0);
}
__device__ __forceinline__ float gelu_exact(float x) {
  return 0.5f * x * (1.0f + erff(x * 0.70710678118654752440f));
}

// ---- problem constants ----
// B=32768, D=768, H1=256, E=128, N=500(pad 512), K_imp=902(pad 960)

// ---------------------------------------------------------------------------
// prep: W1T via coalesced LDS-tile transpose (blocks 0..47); rest idx-based.
// ---------------------------------------------------------------------------
__global__ __launch_bounds__(256) void k_prep(
    const float* __restrict__ enc_w1, const float* __restrict__ enc_w2,
    const float* __restrict__ imp_w1, const float* __restrict__ cent,
    const float* __restrict__ reward, const float* __restrict__ tsp,
    const float* __restrict__ emo,
    unsigned short* __restrict__ W1T, unsigned short* __restrict__ W2T,
    unsigned short* __restrict__ impW1T, unsigned short* __restrict__ centC,
    float* __restrict__ c_n, unsigned short* __restrict__ tail) {
  __shared__ float ld[64][65];
  const int bx = blockIdx.x, t = threadIdx.x;
  if (bx < 48) {                       // W1T [256 n][768 k] row-major
    int tk = bx % 12, tn = bx / 12;
    int k0 = tk * 64, n0 = tn * 64;
    int cn = t & 63, r4 = t >> 6;
#pragma unroll
    for (int pass = 0; pass < 16; ++pass) {
      int kk = pass * 4 + r4;
      ld[kk][cn] = enc_w1[(size_t)(k0 + kk) * 256 + n0 + cn];
    }
    __syncthreads();
    int ck = t & 63, rn4 = t >> 6;
#pragma unroll
    for (int pass = 0; pass < 16; ++pass) {
      int nn = pass * 4 + rn4;
      W1T[(size_t)(n0 + nn) * 768 + k0 + ck] = f32_to_f16u(ld[ck][nn]);
    }
    return;
  }
  int idx = (bx - 48) * 256 + t;
  if (idx < 128 * 256) {               // W2T [128][256]
    int n = idx >> 8, k = idx & 255;
    W2T[idx] = f32_to_f16u(enc_w2[k * 128 + n]);
  }
  if (idx < 64 * 960) {                // impW1T [64][960], k>=902 zero
    int n = idx / 960, k = idx - n * 960;
    impW1T[idx] = (k < 902) ? f32_to_f16u(imp_w1[k * 64 + n]) : (unsigned short)0;
  }
  if (idx < 512 * 128) {               // centC [512][128], rows>=500 zero
    int n = idx >> 7, k = idx & 127;
    centC[idx] = (n < 500) ? f32_to_f16u(cent[n * 128 + k]) : (unsigned short)0;
  }
  if (idx < 512) {                     // centroid norms (of f16-rounded values)
    float s = 0.f;
    if (idx < 500) {
      const f32x4* p = (const f32x4*)(cent + idx * 128);
#pragma unroll 8
      for (int j = 0; j < 32; ++j) {
        f32x4 v = p[j];
#pragma unroll
        for (int e = 0; e < 4; ++e) {
          float q = (float)(_Float16)v[e];
          s += q * q;
        }
      }
    }
    c_n[idx] = sqrtf(s);
  }
  if (idx < 32768) {                   // tail pack
    f32x4 e4 = *(const f32x4*)(emo + (size_t)idx * 4);
    unsigned short* tp = tail + (size_t)idx * 8;
    tp[0] = f32_to_f16u(reward[idx]);
    tp[1] = f32_to_f16u(tsp[idx]);
    tp[2] = f32_to_f16u(e4[0]); tp[3] = f32_to_f16u(e4[1]);
    tp[4] = f32_to_f16u(e4[2]); tp[5] = f32_to_f16u(e4[3]);
    tp[6] = 0; tp[7] = 0;
  }
}

// ---------------------------------------------------------------------------
// k_fused: entire op. Main loop = EXACT r6 structure (proven best).
// 64 rows/block, 512 blocks (2/CU), 512 thr (8 waves).
// Main-loop LDS 72KB: A dbuf 2x8K | tail 8K | B1 32K | B2 dbuf 2x8K.
// Epilogue LDS reuse: h1 [0,32K) -> enc2 (W2T halves [32K,64K)) ->
// enc tile [0,16K) -> sims (cent chunks [32K,64K)) + top5 merge.
// s_pn@65536 s_en@67584 s_p@67840 s_mk@68864. No h1/enc global traffic.
// ---------------------------------------------------------------------------
__global__ __launch_bounds__(512, 4) void k_fused(
    const float* __restrict__ cue, const float* __restrict__ internal,
    const float* __restrict__ emo,
    const unsigned short* __restrict__ W1T, const unsigned short* __restrict__ impW1T,
    const unsigned short* __restrict__ tail,
    const unsigned short* __restrict__ W2T, const unsigned short* __restrict__ centC,
    const float* __restrict__ c_n,
    const float* __restrict__ b1, const float* __restrict__ b2,
    const float* __restrict__ ib1, const float* __restrict__ iw2,
    const float* __restrict__ ib2, float* __restrict__ out) {
  __shared__ unsigned char sm[73728];
  const int t = threadIdx.x;
  const int lane = t & 63, w = t >> 6;
  const int wr = w >> 2, wc = w & 3;
  const int g = lane >> 4, c = lane & 15;
  const int row0 = blockIdx.x * 64;

  const int srow = t >> 3, q8 = t & 7;
  const int abyte = srow * 128 + q8 * 16;
  const int aswz = (srow & 7) << 4;
  const int myrow = row0 + srow;

  f32x4 aLo, aHi;
  auto issueA = [&](int j) {
    const float* s = (j < 12)
        ? (cue + (size_t)myrow * 768 + j * 64 + q8 * 8)
        : (internal + (size_t)myrow * 128 + (j - 12) * 64 + q8 * 8);
    aLo = *(const f32x4*)s;
    aHi = *(const f32x4*)(s + 4);
  };
  auto convWrite = [&](int buf) {
    uint4v u = {pk2(aLo[0], aLo[1]), pk2(aLo[2], aLo[3]),
                pk2(aHi[0], aHi[1]), pk2(aHi[2], aHi[3])};
    *(uint4v*)(sm + buf * 8192 + (abyte ^ aswz)) = u;
  };
  auto issueB1 = [&](int j) {
#pragma unroll
    for (int i = 0; i < 4; ++i) {
      int L = i * 8192 + t * 16;
      int nl = L >> 7, x = L & 127;
      gload_lds16(sm + 24576 + i * 8192 + w * 1024,
                  (const unsigned char*)W1T + ((size_t)nl * 768 + j * 64) * 2 +
                      (x ^ ((nl & 7) << 4)));
    }
  };
  auto issueB2 = [&](int j, int buf) {
    int L = t * 16, nl = L >> 7, x = L & 127;
    gload_lds16(sm + 57344 + buf * 8192 + w * 1024,
                (const unsigned char*)impW1T + (size_t)nl * 1920 + j * 128 +
                    (x ^ ((nl & 7) << 4)));
  };

  f32x4 acc1[2][4];
  f32x4 acc2[2];
#pragma unroll
  for (int i = 0; i < 2; ++i) {
    acc2[i] = f32x4{0.f, 0.f, 0.f, 0.f};
#pragma unroll
    for (int j = 0; j < 4; ++j) acc1[i][j] = f32x4{0.f, 0.f, 0.f, 0.f};
  }

  auto mfma_step = [&](int abuf, int b2buf, bool enc) {
    const unsigned char* Ab  = sm + abuf * 8192;
    const unsigned char* Bb2 = sm + 57344 + b2buf * 8192;
#pragma unroll
    for (int ks = 0; ks < 2; ++ks) {
      half8 af[2];
#pragma unroll
      for (int mf = 0; mf < 2; ++mf) {
        int m = wr * 32 + mf * 16 + c;
        af[mf] = *(const half8*)(Ab + m * 128 + ((ks * 64 + g * 16) ^ ((m & 7) << 4)));
      }
      {
        int n2 = wc * 16 + c;
        half8 b2f = *(const half8*)(Bb2 + n2 * 128 + ((ks * 64 + g * 16) ^ ((n2 & 7) << 4)));
        acc2[0] = mfma16(af[0], b2f, acc2[0]);
        acc2[1] = mfma16(af[1], b2f, acc2[1]);
      }
      if (enc) {
#pragma unroll
        for (int nf = 0; nf < 4; ++nf) {
          int n = wc * 64 + nf * 16 + c;
          half8 bf = *(const half8*)(sm + 24576 + n * 128 +
                                     ((ks * 64 + g * 16) ^ ((n & 7) << 4)));
          acc1[0][nf] = mfma16(af[0], bf, acc1[0][nf]);
          acc1[1][nf] = mfma16(af[1], bf, acc1[1][nf]);
        }
      }
    }
  };

  // ---- prologue ----
  {
    uint4v tl = {0u, 0u, 0u, 0u};
    if (q8 == 0) tl = *(const uint4v*)(tail + (size_t)myrow * 8);
    issueA(0); issueB1(0); issueB2(0, 0);
    *(uint4v*)(sm + 16384 + (abyte ^ aswz)) = tl;
    convWrite(0);
    issueA(1); issueB2(1, 1);
    WAITV(3);
    LGKM0;
    __builtin_amdgcn_s_barrier();
  }

  int p = 0;
  for (int it = 0; it < 12; ++it) {
    mfma_step(p, p, true);
    convWrite(p ^ 1);
    LGKM0;
    __builtin_amdgcn_s_barrier();
    if (it < 11) issueB1(it + 1);
    issueA(it + 2);
    issueB2(it + 2, p);
    WAITV(3);
    __builtin_amdgcn_s_barrier();
    p ^= 1;
  }
  mfma_step(0, 0, false);              // tile 12
  convWrite(1);                        // A(13)
  LGKM0;
  __builtin_amdgcn_s_barrier();
  issueB2(14, 0);
  WAITV(1);
  __builtin_amdgcn_s_barrier();
  mfma_step(1, 1, false);              // tile 13
  LGKM0;
  __builtin_amdgcn_s_barrier();
  WAITV(0);
  __builtin_amdgcn_s_barrier();
  mfma_step(2, 0, false);              // tile 14 (tail slot)

  // ================= EPILOGUE (all in-LDS) =================
  float* s_pn = (float*)(sm + 65536);        // [64][8]
  float* s_en = (float*)(sm + 67584);        // [64]
  float* s_p  = (float*)(sm + 67840);        // [64][4]
  unsigned int* s_mk = (unsigned int*)(sm + 68864);  // [64][2][5]

  __syncthreads();   // all mfma reads of sm complete

  // imp partials (acc2) + h1 tile -> LDS [64 rows][512 B] swizzled
  {
    float b1v = ib1[wc * 16 + c];
    float w2v = iw2[wc * 16 + c];
#pragma unroll
    for (int mf = 0; mf < 2; ++mf)
#pragma unroll
      for (int rr = 0; rr < 4; ++rr) {
        float v = gelu_exact(acc2[mf][rr] + b1v) * w2v;
        v += __shfl_xor(v, 1);
        v += __shfl_xor(v, 2);
        v += __shfl_xor(v, 4);
        v += __shfl_xor(v, 8);
        if (c == 0) s_p[(wr * 32 + mf * 16 + g * 4 + rr) * 4 + wc] = v;
      }
    float bias1[4];
#pragma unroll
    for (int nf = 0; nf < 4; ++nf) bias1[nf] = b1[wc * 64 + nf * 16 + c];
#pragma unroll
    for (int mf = 0; mf < 2; ++mf)
#pragma unroll
      for (int nf = 0; nf < 4; ++nf)
#pragma unroll
        for (int rr = 0; rr < 4; ++rr) {
          int row = wr * 32 + mf * 16 + g * 4 + rr;
          int col = wc * 64 + nf * 16 + c;
          float x = gelu_exact(acc1[mf][nf][rr] + bias1[nf]);
          *(unsigned short*)(sm + row * 512 + ((col * 2) ^ ((row & 7) << 4))) =
              f32_to_f16u(x);
        }
  }
  __syncthreads();

  // imp final (t<64) -> out col 5
  if (t < 64) {
    float ssum = s_p[t * 4 + 0] + s_p[t * 4 + 1] + s_p[t * 4 + 2] + s_p[t * 4 + 3];
    int rowA = row0 + t;
    float z = ssum + ib2[0];
    float sig = 1.0f / (1.0f + expf(-z));
    f32x4 e4 = *(const f32x4*)(emo + (size_t)rowA * 4);
    float m4 = 0.25f * (e4[0] + e4[1] + e4[2] + e4[3]);
    out[(size_t)rowA * 6 + 5] = sig * m4;
  }

  // enc2: K=256 in two halves; wave w owns cols w*16..w*16+16
  f32x4 acc_e[4];
#pragma unroll
  for (int mf = 0; mf < 4; ++mf) acc_e[mf] = f32x4{0.f, 0.f, 0.f, 0.f};
#pragma unroll
  for (int kh = 0; kh < 2; ++kh) {
    // stage W2T k-half: [128 n][256 B] at sm+32768
#pragma unroll
    for (int i = 0; i < 4; ++i) {
      int L = i * 8192 + t * 16;
      int nl = L >> 8, x = L & 255;
      gload_lds16(sm + 32768 + i * 8192 + w * 1024,
                  (const unsigned char*)W2T + (size_t)nl * 512 + kh * 256 +
                      (x ^ ((nl & 7) << 4)));
    }
    __syncthreads();
#pragma unroll
    for (int ks = 0; ks < 4; ++ks) {
      half8 af[4];
#pragma unroll
      for (int mf = 0; mf < 4; ++mf) {
        int m = mf * 16 + c;
        af[mf] = *(const half8*)(sm + m * 512 +
                                 ((kh * 256 + ks * 64 + g * 16) ^ ((m & 7) << 4)));
      }
      int nl = w * 16 + c;
      half8 bf = *(const half8*)(sm + 32768 + nl * 256 +
                                 ((ks * 64 + g * 16) ^ ((nl & 7) << 4)));
#pragma unroll
      for (int mf = 0; mf < 4; ++mf) acc_e[mf] = mfma16(af[mf], bf, acc_e[mf]);
    }
    __syncthreads();   // reads done before restage / h1 overwrite
  }

  // enc tile [64][256 B] swizzled at sm[0,16K) (h1 dead) + norms from regs
  {
    float bias2 = b2[w * 16 + c];
#pragma unroll
    for (int mf = 0; mf < 4; ++mf)
#pragma unroll
      for (int rr = 0; rr < 4; ++rr) {
        int row = mf * 16 + g * 4 + rr;
        float x = acc_e[mf][rr] + bias2;
        unsigned short hv = f32_to_f16u(x);
        float xr = f16u_to_f32(hv);
        *(unsigned short*)(sm + row * 256 + (((w * 16 + c) * 2) ^ ((row & 7) << 4))) = hv;
        float v = xr * xr;
        v += __shfl_xor(v, 1);
        v += __shfl_xor(v, 2);
        v += __shfl_xor(v, 4);
        v += __shfl_xor(v, 8);
        if (c == 0) s_pn[row * 8 + w] = v;
      }
  }
  __syncthreads();
  if (t < 64) {
    float s = 0.f;
#pragma unroll
    for (int i = 0; i < 8; ++i) s += s_pn[t * 8 + i];
    s_en[t] = sqrtf(s);
  }
  __syncthreads();

  // sims: wave pair (w, w+4) shares rows (w&3)*16..+16; halfsel splits cols
  const int rlb = (w & 3) * 16;
  const int halfsel = w >> 2;
  float en[4];
#pragma unroll
  for (int r = 0; r < 4; ++r) en[r] = s_en[rlb + g * 4 + r];
  half8 af2[4];
  {
    int rl = rlb + c;
#pragma unroll
    for (int kk = 0; kk < 4; ++kk)
      af2[kk] = *(const half8*)(sm + rl * 256 +
                                ((kk * 64 + g * 16) ^ ((rl & 7) << 4)));
  }

  unsigned int top5[4][5];
#pragma unroll
  for (int r = 0; r < 4; ++r)
#pragma unroll
    for (int s5 = 0; s5 < 5; ++s5) top5[r][s5] = 0u;

#pragma unroll
  for (int ch = 0; ch < 4; ++ch) {
    __syncthreads();
#pragma unroll
    for (int i = 0; i < 4; ++i) {   // stage cent chunk [128][256B] at sm+32768
      int L = i * 8192 + t * 16;
      int nl = L >> 8, x = L & 255;
      gload_lds16(sm + 32768 + i * 8192 + w * 1024,
                  (const unsigned char*)centC + (size_t)(ch * 128 + nl) * 256 +
                      (x ^ ((nl & 7) << 4)));
    }
    __syncthreads();
#pragma unroll
    for (int nfc = 0; nfc < 4; ++nfc) {
      int nl = halfsel * 64 + nfc * 16 + c;
      const unsigned char* bbase = sm + 32768 + nl * 256;
      int swz = (nl & 7) << 4;
      f32x4 acc = f32x4{0.f, 0.f, 0.f, 0.f};
#pragma unroll
      for (int kk = 0; kk < 4; ++kk) {
        half8 bf = *(const half8*)(bbase + ((kk * 64 + g * 16) ^ swz));
        acc = mfma16(af2[kk], bf, acc);
      }
      int col = ch * 128 + nl;
      float cnv = c_n[col];
#pragma unroll
      for (int r = 0; r < 4; ++r) {
        float denom = fmaxf(en[r] * cnv, 1e-8f);
        float v = acc[r] * __builtin_amdgcn_rcpf(denom);
        unsigned int u = __float_as_uint(v);
        u = (u & 0x80000000u) ? ~u : (u | 0x80000000u);
        unsigned int k = (col < 500) ? ((u & 0xFFFFFE00u) | (unsigned)col) : 0u;
        unsigned int t0 = top5[r][0], t1 = top5[r][1], t2 = top5[r][2],
                     t3 = top5[r][3], t4 = top5[r][4];
        top5[r][0] = (k > t0) ? k : t0;
        top5[r][1] = (k > t0) ? t0 : ((k > t1) ? k : t1);
        top5[r][2] = (k > t1) ? t1 : ((k > t2) ? k : t2);
        top5[r][3] = (k > t2) ? t2 : ((k > t3) ? k : t3);
        top5[r][4] = (k > t3) ? t3 : ((k > t4) ? k : t4);
      }
    }
  }

  // per-wave extraction -> s_mk[row][halfsel][5]
#pragma unroll
  for (int r = 0; r < 4; ++r) {
    int row = rlb + g * 4 + r;
    unsigned int h0 = top5[r][0], h1v = top5[r][1], h2 = top5[r][2],
                 h3 = top5[r][3], h4 = top5[r][4];
#pragma unroll
    for (int it5 = 0; it5 < 5; ++it5) {
      unsigned int best = h0;
#pragma unroll
      for (int s = 1; s < 16; s <<= 1) {
        unsigned int o = __shfl_xor(best, s);
        best = (o > best) ? o : best;
      }
      if (c == 0) s_mk[(row * 2 + halfsel) * 5 + it5] = best;
      bool pop = (h0 == best);
      h0 = pop ? h1v : h0;
      h1v = pop ? h2 : h1v;
      h2 = pop ? h3 : h2;
      h3 = pop ? h4 : h3;
      h4 = pop ? 0u : h4;
    }
  }
  __syncthreads();

  // merge two sorted 5-lists per row -> out cols 0..4
  if (t < 64) {
    const unsigned int* A = s_mk + (t * 2 + 0) * 5;
    const unsigned int* B = s_mk + (t * 2 + 1) * 5;
    int ia = 0, ib = 0;
#pragma unroll
    for (int o = 0; o < 5; ++o) {
      unsigned int a = (ia < 5) ? A[ia] : 0u;
      unsigned int b = (ib < 5) ? B[ib] : 0u;
      unsigned int best;
      if (a >= b) { best = a; ++ia; } else { best = b; ++ib; }
      unsigned int m = best & 0xFFFFFE00u;
      unsigned int uu = (m & 0x80000000u) ? (m ^ 0x80000000u) : ~m;
      out[(size_t)(row0 + t) * 6 + o] = __uint_as_float(uu);
    }
  }
}

// ---------------------------------------------------------------------------
extern "C" void kernel_launch(void* const* d_in, const int* in_sizes, int n_in,
                              void* d_out, int out_size, void* d_ws, size_t ws_size,
                              hipStream_t stream) {
  (void)in_sizes; (void)n_in; (void)out_size; (void)ws_size;
  const float* cue      = (const float*)d_in[0];
  const float* internal = (const float*)d_in[1];
  const float* reward   = (const float*)d_in[2];
  const float* tsp      = (const float*)d_in[3];
  const float* emo      = (const float*)d_in[4];
  const float* cent     = (const float*)d_in[5];
  const float* enc_w1   = (const float*)d_in[6];
  const float* enc_b1   = (const float*)d_in[7];
  const float* enc_w2   = (const float*)d_in[8];
  const float* enc_b2   = (const float*)d_in[9];
  const float* imp_w1   = (const float*)d_in[10];
  const float* imp_b1   = (const float*)d_in[11];
  const float* imp_w2   = (const float*)d_in[12];
  const float* imp_b2   = (const float*)d_in[13];
  float* out = (float*)d_out;

  unsigned char* ws = (unsigned char*)d_ws;
  unsigned short* W1T    = (unsigned short*)(ws + 0);        // 393216
  unsigned short* W2T    = (unsigned short*)(ws + 393216);   //  65536
  unsigned short* impW1T = (unsigned short*)(ws + 458752);   // 122880
  unsigned short* centC  = (unsigned short*)(ws + 581632);   // 131072
  float*          c_n    = (float*)(ws + 712704);            //   2048
  unsigned short* tail   = (unsigned short*)(ws + 714752);   // 524288

  k_prep<<<304, 256, 0, stream>>>(enc_w1, enc_w2, imp_w1, cent, reward, tsp, emo,
                                  W1T, W2T, impW1T, centC, c_n, tail);
  k_fused<<<512, 512, 0, stream>>>(cue, internal, emo, W1T, impW1T, tail,
                                   W2T, centC, c_n, enc_b1, enc_b2,
                                   imp_b1, imp_w2, imp_b2, out);
}

// Round 14
// 63.028 us; speedup vs baseline: 1.0939x; 1.0072x over previous
//
#include <hip/hip_runtime.h>
#include <hip/hip_bf16.h>
#include <hip/hip_fp16.h>
#include <math.h>

// ---- types ----
using f32x4  = __attribute__((ext_vector_type(4))) float;
using half8  = __attribute__((ext_vector_type(8))) _Float16;
using uint4v = __attribute__((ext_vector_type(4))) unsigned int;

#define WAITV(N) asm volatile("s_waitcnt vmcnt(" #N ")" ::: "memory")
#define LGKM0    asm volatile("s_waitcnt lgkmcnt(0)" ::: "memory")

__device__ __forceinline__ unsigned short f32_to_f16u(float f) {
  return __half_as_ushort(__float2half(f));
}
__device__ __forceinline__ float f16u_to_f32(unsigned short h) {
  return __half2float(__ushort_as_half(h));
}
__device__ __forceinline__ unsigned int pk2(float a, float b) {
  return (unsigned int)f32_to_f16u(a) | ((unsigned int)f32_to_f16u(b) << 16);
}
__device__ __forceinline__ f32x4 mfma16(half8 a, half8 b, f32x4 c) {
  return __builtin_amdgcn_mfma_f32_16x16x32_f16(a, b, c, 0, 0, 0);
}
__device__ __forceinline__ void gload_lds16(void* lds, const void* g) {
  __builtin_amdgcn_global_load_lds(
      (const __attribute__((address_space(1))) unsigned int*)g,
      (__attribute__((address_space(3))) unsigned int*)lds, 16, 0, 0);
}
__device__ __forceinline__ float gelu_exact(float x) {
  return 0.5f * x * (1.0f + erff(x * 0.70710678118654752440f));
}

// ---- problem constants ----
// B=32768, D=768, H1=256, E=128, N=500(pad 512), K_imp=902(pad 960)

// ---------------------------------------------------------------------------
// prep: W1T via coalesced LDS-tile transpose (blocks 0..47); rest idx-based.
// ---------------------------------------------------------------------------
__global__ __launch_bounds__(256) void k_prep(
    const float* __restrict__ enc_w1, const float* __restrict__ enc_w2,
    const float* __restrict__ imp_w1, const float* __restrict__ cent,
    const float* __restrict__ reward, const float* __restrict__ tsp,
    const float* __restrict__ emo,
    unsigned short* __restrict__ W1T, unsigned short* __restrict__ W2T,
    unsigned short* __restrict__ impW1T, unsigned short* __restrict__ centC,
    float* __restrict__ c_n, unsigned short* __restrict__ tail) {
  __shared__ float ld[64][65];
  const int bx = blockIdx.x, t = threadIdx.x;
  if (bx < 48) {                       // W1T [256 n][768 k] row-major
    int tk = bx % 12, tn = bx / 12;
    int k0 = tk * 64, n0 = tn * 64;
    int cn = t & 63, r4 = t >> 6;
#pragma unroll
    for (int pass = 0; pass < 16; ++pass) {
      int kk = pass * 4 + r4;
      ld[kk][cn] = enc_w1[(size_t)(k0 + kk) * 256 + n0 + cn];
    }
    __syncthreads();
    int ck = t & 63, rn4 = t >> 6;
#pragma unroll
    for (int pass = 0; pass < 16; ++pass) {
      int nn = pass * 4 + rn4;
      W1T[(size_t)(n0 + nn) * 768 + k0 + ck] = f32_to_f16u(ld[ck][nn]);
    }
    return;
  }
  int idx = (bx - 48) * 256 + t;
  if (idx < 128 * 256) {               // W2T [128][256]
    int n = idx >> 8, k = idx & 255;
    W2T[idx] = f32_to_f16u(enc_w2[k * 128 + n]);
  }
  if (idx < 64 * 960) {                // impW1T [64][960], k>=902 zero
    int n = idx / 960, k = idx - n * 960;
    impW1T[idx] = (k < 902) ? f32_to_f16u(imp_w1[k * 64 + n]) : (unsigned short)0;
  }
  if (idx < 512 * 128) {               // centC [512][128], rows>=500 zero
    int n = idx >> 7, k = idx & 127;
    centC[idx] = (n < 500) ? f32_to_f16u(cent[n * 128 + k]) : (unsigned short)0;
  }
  if (idx < 512) {                     // centroid norms (of f16-rounded values)
    float s = 0.f;
    if (idx < 500) {
      const f32x4* p = (const f32x4*)(cent + idx * 128);
#pragma unroll 8
      for (int j = 0; j < 32; ++j) {
        f32x4 v = p[j];
#pragma unroll
        for (int e = 0; e < 4; ++e) {
          float q = (float)(_Float16)v[e];
          s += q * q;
        }
      }
    }
    c_n[idx] = sqrtf(s);
  }
  if (idx < 32768) {                   // tail pack
    f32x4 e4 = *(const f32x4*)(emo + (size_t)idx * 4);
    unsigned short* tp = tail + (size_t)idx * 8;
    tp[0] = f32_to_f16u(reward[idx]);
    tp[1] = f32_to_f16u(tsp[idx]);
    tp[2] = f32_to_f16u(e4[0]); tp[3] = f32_to_f16u(e4[1]);
    tp[4] = f32_to_f16u(e4[2]); tp[5] = f32_to_f16u(e4[3]);
    tp[6] = 0; tp[7] = 0;
  }
}

// ---------------------------------------------------------------------------
// k_fused: entire op. Main loop = EXACT r6 structure (proven best).
// 64 rows/block, 512 blocks (2/CU), 512 thr (8 waves).
// Main-loop LDS 72KB: A dbuf 2x8K | tail 8K | B1 32K | B2 dbuf 2x8K.
// Epilogue LDS reuse: h1 [0,32K) -> enc2 (W2T halves [32K,64K)) ->
// enc tile [0,16K) -> sims (cent chunks [32K,64K)) + top5 merge.
// s_pn@65536 s_en@67584 s_p@67840 s_mk@68864. No h1/enc global traffic.
// ---------------------------------------------------------------------------
__global__ __launch_bounds__(512, 4) void k_fused(
    const float* __restrict__ cue, const float* __restrict__ internal,
    const float* __restrict__ emo,
    const unsigned short* __restrict__ W1T, const unsigned short* __restrict__ impW1T,
    const unsigned short* __restrict__ tail,
    const unsigned short* __restrict__ W2T, const unsigned short* __restrict__ centC,
    const float* __restrict__ c_n,
    const float* __restrict__ b1, const float* __restrict__ b2,
    const float* __restrict__ ib1, const float* __restrict__ iw2,
    const float* __restrict__ ib2, float* __restrict__ out) {
  __shared__ unsigned char sm[73728];
  const int t = threadIdx.x;
  const int lane = t & 63, w = t >> 6;
  const int wr = w >> 2, wc = w & 3;
  const int g = lane >> 4, c = lane & 15;
  const int row0 = blockIdx.x * 64;

  const int srow = t >> 3, q8 = t & 7;
  const int abyte = srow * 128 + q8 * 16;
  const int aswz = (srow & 7) << 4;
  const int myrow = row0 + srow;

  f32x4 aLo, aHi;
  auto issueA = [&](int j) {
    const float* s = (j < 12)
        ? (cue + (size_t)myrow * 768 + j * 64 + q8 * 8)
        : (internal + (size_t)myrow * 128 + (j - 12) * 64 + q8 * 8);
    aLo = *(const f32x4*)s;
    aHi = *(const f32x4*)(s + 4);
  };
  auto convWrite = [&](int buf) {
    uint4v u = {pk2(aLo[0], aLo[1]), pk2(aLo[2], aLo[3]),
                pk2(aHi[0], aHi[1]), pk2(aHi[2], aHi[3])};
    *(uint4v*)(sm + buf * 8192 + (abyte ^ aswz)) = u;
  };
  auto issueB1 = [&](int j) {
#pragma unroll
    for (int i = 0; i < 4; ++i) {
      int L = i * 8192 + t * 16;
      int nl = L >> 7, x = L & 127;
      gload_lds16(sm + 24576 + i * 8192 + w * 1024,
                  (const unsigned char*)W1T + ((size_t)nl * 768 + j * 64) * 2 +
                      (x ^ ((nl & 7) << 4)));
    }
  };
  auto issueB2 = [&](int j, int buf) {
    int L = t * 16, nl = L >> 7, x = L & 127;
    gload_lds16(sm + 57344 + buf * 8192 + w * 1024,
                (const unsigned char*)impW1T + (size_t)nl * 1920 + j * 128 +
                    (x ^ ((nl & 7) << 4)));
  };

  f32x4 acc1[2][4];
  f32x4 acc2[2];
#pragma unroll
  for (int i = 0; i < 2; ++i) {
    acc2[i] = f32x4{0.f, 0.f, 0.f, 0.f};
#pragma unroll
    for (int j = 0; j < 4; ++j) acc1[i][j] = f32x4{0.f, 0.f, 0.f, 0.f};
  }

  auto mfma_step = [&](int abuf, int b2buf, bool enc) {
    const unsigned char* Ab  = sm + abuf * 8192;
    const unsigned char* Bb2 = sm + 57344 + b2buf * 8192;
#pragma unroll
    for (int ks = 0; ks < 2; ++ks) {
      half8 af[2];
#pragma unroll
      for (int mf = 0; mf < 2; ++mf) {
        int m = wr * 32 + mf * 16 + c;
        af[mf] = *(const half8*)(Ab + m * 128 + ((ks * 64 + g * 16) ^ ((m & 7) << 4)));
      }
      {
        int n2 = wc * 16 + c;
        half8 b2f = *(const half8*)(Bb2 + n2 * 128 + ((ks * 64 + g * 16) ^ ((n2 & 7) << 4)));
        acc2[0] = mfma16(af[0], b2f, acc2[0]);
        acc2[1] = mfma16(af[1], b2f, acc2[1]);
      }
      if (enc) {
#pragma unroll
        for (int nf = 0; nf < 4; ++nf) {
          int n = wc * 64 + nf * 16 + c;
          half8 bf = *(const half8*)(sm + 24576 + n * 128 +
                                     ((ks * 64 + g * 16) ^ ((n & 7) << 4)));
          acc1[0][nf] = mfma16(af[0], bf, acc1[0][nf]);
          acc1[1][nf] = mfma16(af[1], bf, acc1[1][nf]);
        }
      }
    }
  };

  // ---- prologue ----
  {
    uint4v tl = {0u, 0u, 0u, 0u};
    if (q8 == 0) tl = *(const uint4v*)(tail + (size_t)myrow * 8);
    issueA(0); issueB1(0); issueB2(0, 0);
    *(uint4v*)(sm + 16384 + (abyte ^ aswz)) = tl;
    convWrite(0);
    issueA(1); issueB2(1, 1);
    WAITV(3);
    LGKM0;
    __builtin_amdgcn_s_barrier();
  }

  int p = 0;
  for (int it = 0; it < 12; ++it) {
    mfma_step(p, p, true);
    convWrite(p ^ 1);
    LGKM0;
    __builtin_amdgcn_s_barrier();
    if (it < 11) issueB1(it + 1);
    issueA(it + 2);
    issueB2(it + 2, p);
    WAITV(3);
    __builtin_amdgcn_s_barrier();
    p ^= 1;
  }
  mfma_step(0, 0, false);              // tile 12
  convWrite(1);                        // A(13)
  LGKM0;
  __builtin_amdgcn_s_barrier();
  issueB2(14, 0);
  WAITV(1);
  __builtin_amdgcn_s_barrier();
  mfma_step(1, 1, false);              // tile 13
  LGKM0;
  __builtin_amdgcn_s_barrier();
  WAITV(0);
  __builtin_amdgcn_s_barrier();
  mfma_step(2, 0, false);              // tile 14 (tail slot)

  // ================= EPILOGUE (all in-LDS) =================
  float* s_pn = (float*)(sm + 65536);        // [64][8]
  float* s_en = (float*)(sm + 67584);        // [64]
  float* s_p  = (float*)(sm + 67840);        // [64][4]
  unsigned int* s_mk = (unsigned int*)(sm + 68864);  // [64][2][5]

  __syncthreads();   // all mfma reads of sm complete

  // imp partials (acc2) + h1 tile -> LDS [64 rows][512 B] swizzled
  {
    float b1v = ib1[wc * 16 + c];
    float w2v = iw2[wc * 16 + c];
#pragma unroll
    for (int mf = 0; mf < 2; ++mf)
#pragma unroll
      for (int rr = 0; rr < 4; ++rr) {
        float v = gelu_exact(acc2[mf][rr] + b1v) * w2v;
        v += __shfl_xor(v, 1);
        v += __shfl_xor(v, 2);
        v += __shfl_xor(v, 4);
        v += __shfl_xor(v, 8);
        if (c == 0) s_p[(wr * 32 + mf * 16 + g * 4 + rr) * 4 + wc] = v;
      }
    float bias1[4];
#pragma unroll
    for (int nf = 0; nf < 4; ++nf) bias1[nf] = b1[wc * 64 + nf * 16 + c];
#pragma unroll
    for (int mf = 0; mf < 2; ++mf)
#pragma unroll
      for (int nf = 0; nf < 4; ++nf)
#pragma unroll
        for (int rr = 0; rr < 4; ++rr) {
          int row = wr * 32 + mf * 16 + g * 4 + rr;
          int col = wc * 64 + nf * 16 + c;
          float x = gelu_exact(acc1[mf][nf][rr] + bias1[nf]);
          *(unsigned short*)(sm + row * 512 + ((col * 2) ^ ((row & 7) << 4))) =
              f32_to_f16u(x);
        }
  }
  __syncthreads();

  // imp final (t<64) -> out col 5
  if (t < 64) {
    float ssum = s_p[t * 4 + 0] + s_p[t * 4 + 1] + s_p[t * 4 + 2] + s_p[t * 4 + 3];
    int rowA = row0 + t;
    float z = ssum + ib2[0];
    float sig = 1.0f / (1.0f + expf(-z));
    f32x4 e4 = *(const f32x4*)(emo + (size_t)rowA * 4);
    float m4 = 0.25f * (e4[0] + e4[1] + e4[2] + e4[3]);
    out[(size_t)rowA * 6 + 5] = sig * m4;
  }

  // enc2: K=256 in two halves; wave w owns cols w*16..w*16+16
  f32x4 acc_e[4];
#pragma unroll
  for (int mf = 0; mf < 4; ++mf) acc_e[mf] = f32x4{0.f, 0.f, 0.f, 0.f};
#pragma unroll
  for (int kh = 0; kh < 2; ++kh) {
    // stage W2T k-half: [128 n][256 B] at sm+32768
#pragma unroll
    for (int i = 0; i < 4; ++i) {
      int L = i * 8192 + t * 16;
      int nl = L >> 8, x = L & 255;
      gload_lds16(sm + 32768 + i * 8192 + w * 1024,
                  (const unsigned char*)W2T + (size_t)nl * 512 + kh * 256 +
                      (x ^ ((nl & 7) << 4)));
    }
    __syncthreads();
#pragma unroll
    for (int ks = 0; ks < 4; ++ks) {
      half8 af[4];
#pragma unroll
      for (int mf = 0; mf < 4; ++mf) {
        int m = mf * 16 + c;
        af[mf] = *(const half8*)(sm + m * 512 +
                                 ((kh * 256 + ks * 64 + g * 16) ^ ((m & 7) << 4)));
      }
      int nl = w * 16 + c;
      half8 bf = *(const half8*)(sm + 32768 + nl * 256 +
                                 ((ks * 64 + g * 16) ^ ((nl & 7) << 4)));
#pragma unroll
      for (int mf = 0; mf < 4; ++mf) acc_e[mf] = mfma16(af[mf], bf, acc_e[mf]);
    }
    __syncthreads();   // reads done before restage / h1 overwrite
  }

  // enc tile [64][256 B] swizzled at sm[0,16K) (h1 dead) + norms from regs
  {
    float bias2 = b2[w * 16 + c];
#pragma unroll
    for (int mf = 0; mf < 4; ++mf)
#pragma unroll
      for (int rr = 0; rr < 4; ++rr) {
        int row = mf * 16 + g * 4 + rr;
        float x = acc_e[mf][rr] + bias2;
        unsigned short hv = f32_to_f16u(x);
        float xr = f16u_to_f32(hv);
        *(unsigned short*)(sm + row * 256 + (((w * 16 + c) * 2) ^ ((row & 7) << 4))) = hv;
        float v = xr * xr;
        v += __shfl_xor(v, 1);
        v += __shfl_xor(v, 2);
        v += __shfl_xor(v, 4);
        v += __shfl_xor(v, 8);
        if (c == 0) s_pn[row * 8 + w] = v;
      }
  }
  __syncthreads();
  if (t < 64) {
    float s = 0.f;
#pragma unroll
    for (int i = 0; i < 8; ++i) s += s_pn[t * 8 + i];
    s_en[t] = sqrtf(s);
  }
  __syncthreads();

  // sims: wave pair (w, w+4) shares rows (w&3)*16..+16; halfsel splits cols
  const int rlb = (w & 3) * 16;
  const int halfsel = w >> 2;
  float en[4];
#pragma unroll
  for (int r = 0; r < 4; ++r) en[r] = s_en[rlb + g * 4 + r];
  half8 af2[4];
  {
    int rl = rlb + c;
#pragma unroll
    for (int kk = 0; kk < 4; ++kk)
      af2[kk] = *(const half8*)(sm + rl * 256 +
                                ((kk * 64 + g * 16) ^ ((rl & 7) << 4)));
  }

  unsigned int top5[4][5];
#pragma unroll
  for (int r = 0; r < 4; ++r)
#pragma unroll
    for (int s5 = 0; s5 < 5; ++s5) top5[r][s5] = 0u;

#pragma unroll
  for (int ch = 0; ch < 4; ++ch) {
    __syncthreads();
#pragma unroll
    for (int i = 0; i < 4; ++i) {   // stage cent chunk [128][256B] at sm+32768
      int L = i * 8192 + t * 16;
      int nl = L >> 8, x = L & 255;
      gload_lds16(sm + 32768 + i * 8192 + w * 1024,
                  (const unsigned char*)centC + (size_t)(ch * 128 + nl) * 256 +
                      (x ^ ((nl & 7) << 4)));
    }
    __syncthreads();
#pragma unroll
    for (int nfc = 0; nfc < 4; ++nfc) {
      int nl = halfsel * 64 + nfc * 16 + c;
      const unsigned char* bbase = sm + 32768 + nl * 256;
      int swz = (nl & 7) << 4;
      f32x4 acc = f32x4{0.f, 0.f, 0.f, 0.f};
#pragma unroll
      for (int kk = 0; kk < 4; ++kk) {
        half8 bf = *(const half8*)(bbase + ((kk * 64 + g * 16) ^ swz));
        acc = mfma16(af2[kk], bf, acc);
      }
      int col = ch * 128 + nl;
      float cnv = c_n[col];
#pragma unroll
      for (int r = 0; r < 4; ++r) {
        float denom = fmaxf(en[r] * cnv, 1e-8f);
        float v = acc[r] * __builtin_amdgcn_rcpf(denom);
        unsigned int u = __float_as_uint(v);
        u = (u & 0x80000000u) ? ~u : (u | 0x80000000u);
        unsigned int k = (col < 500) ? ((u & 0xFFFFFE00u) | (unsigned)col) : 0u;
        unsigned int t0 = top5[r][0], t1 = top5[r][1], t2 = top5[r][2],
                     t3 = top5[r][3], t4 = top5[r][4];
        top5[r][0] = (k > t0) ? k : t0;
        top5[r][1] = (k > t0) ? t0 : ((k > t1) ? k : t1);
        top5[r][2] = (k > t1) ? t1 : ((k > t2) ? k : t2);
        top5[r][3] = (k > t2) ? t2 : ((k > t3) ? k : t3);
        top5[r][4] = (k > t3) ? t3 : ((k > t4) ? k : t4);
      }
    }
  }

  // per-wave extraction -> s_mk[row][halfsel][5]
#pragma unroll
  for (int r = 0; r < 4; ++r) {
    int row = rlb + g * 4 + r;
    unsigned int h0 = top5[r][0], h1v = top5[r][1], h2 = top5[r][2],
                 h3 = top5[r][3], h4 = top5[r][4];
#pragma unroll
    for (int it5 = 0; it5 < 5; ++it5) {
      unsigned int best = h0;
#pragma unroll
      for (int s = 1; s < 16; s <<= 1) {
        unsigned int o = __shfl_xor(best, s);
        best = (o > best) ? o : best;
      }
      if (c == 0) s_mk[(row * 2 + halfsel) * 5 + it5] = best;
      bool pop = (h0 == best);
      h0 = pop ? h1v : h0;
      h1v = pop ? h2 : h1v;
      h2 = pop ? h3 : h2;
      h3 = pop ? h4 : h3;
      h4 = pop ? 0u : h4;
    }
  }
  __syncthreads();

  // merge two sorted 5-lists per row -> out cols 0..4
  if (t < 64) {
    const unsigned int* A = s_mk + (t * 2 + 0) * 5;
    const unsigned int* B = s_mk + (t * 2 + 1) * 5;
    int ia = 0, ib = 0;
#pragma unroll
    for (int o = 0; o < 5; ++o) {
      unsigned int a = (ia < 5) ? A[ia] : 0u;
      unsigned int b = (ib < 5) ? B[ib] : 0u;
      unsigned int best;
      if (a >= b) { best = a; ++ia; } else { best = b; ++ib; }
      unsigned int m = best & 0xFFFFFE00u;
      unsigned int uu = (m & 0x80000000u) ? (m ^ 0x80000000u) : ~m;
      out[(size_t)(row0 + t) * 6 + o] = __uint_as_float(uu);
    }
  }
}

// ---------------------------------------------------------------------------
extern "C" void kernel_launch(void* const* d_in, const int* in_sizes, int n_in,
                              void* d_out, int out_size, void* d_ws, size_t ws_size,
                              hipStream_t stream) {
  (void)in_sizes; (void)n_in; (void)out_size; (void)ws_size;
  const float* cue      = (const float*)d_in[0];
  const float* internal = (const float*)d_in[1];
  const float* reward   = (const float*)d_in[2];
  const float* tsp      = (const float*)d_in[3];
  const float* emo      = (const float*)d_in[4];
  const float* cent     = (const float*)d_in[5];
  const float* enc_w1   = (const float*)d_in[6];
  const float* enc_b1   = (const float*)d_in[7];
  const float* enc_w2   = (const float*)d_in[8];
  const float* enc_b2   = (const float*)d_in[9];
  const float* imp_w1   = (const float*)d_in[10];
  const float* imp_b1   = (const float*)d_in[11];
  const float* imp_w2   = (const float*)d_in[12];
  const float* imp_b2   = (const float*)d_in[13];
  float* out = (float*)d_out;

  unsigned char* ws = (unsigned char*)d_ws;
  unsigned short* W1T    = (unsigned short*)(ws + 0);        // 393216
  unsigned short* W2T    = (unsigned short*)(ws + 393216);   //  65536
  unsigned short* impW1T = (unsigned short*)(ws + 458752);   // 122880
  unsigned short* centC  = (unsigned short*)(ws + 581632);   // 131072
  float*          c_n    = (float*)(ws + 712704);            //   2048
  unsigned short* tail   = (unsigned short*)(ws + 714752);   // 524288

  k_prep<<<304, 256, 0, stream>>>(enc_w1, enc_w2, imp_w1, cent, reward, tsp, emo,
                                  W1T, W2T, impW1T, centC, c_n, tail);
  k_fused<<<512, 512, 0, stream>>>(cue, internal, emo, W1T, impW1T, tail,
                                   W2T, centC, c_n, enc_b1, enc_b2,
                                   imp_b1, imp_w2, imp_b2, out);
}